// Round 7
// baseline (336.081 us; speedup 1.0000x reference)
//
#include <hip/hip_runtime.h>

// Attention_Critic on MI355X — round 7: mega-fusion of encoders + projections +
// attention (E never hits HBM; SE computed and consumed in-LDS; only SE+OT stored).
// Critic/stats kept from round 6; mst finalize folded into wprep.
//
// ws layout (bytes):
//   [0,256)        int flag (1 = bf16 inputs, 0 = f32)
//   [256,+163840)  stats partials f32 [8][32][80][2]
//   [164096,+5120) msts f32 [8][80][2]  (mean, rsig — finalized in wprep blk 60)
//   [169216,...)   Wsa_t bf16 [8][128 col][104 k]
//   [382208,...)   Wse_t bf16 [8][128 col][72 k]
//   [529664,...)   Wp_t  bf16 [4 p][3 mat][32 d][136 k]  (mat 0=sel,1=key,2=val)
//   [634112,...)   Wc1t  bf16 [8][128 col][256 k]
//   [1158400,+32M) (unused E slot)
//   [+32M,+64M)    SE  bf16 [8][16384][128]
//   [+64M,+96M)    OT  bf16 [8][16384][128]

typedef unsigned short u16;
typedef unsigned int u32;

#define NA 8
#define BATCH 16384
#define SD 64
#define AD 16
#define IND 80
#define HID 128
#define HEADS 4
#define ATT 32
#define EPS 1e-5f
#define KP 136    // u16 stride, 128-k tiles
#define KP3 104   // u16 stride, 96-k tiles (Wsa_t)
#define KPS 72    // u16 stride, 64-k tiles (Wse_t)
#define SP 34     // u16 stride, 32-wide sel/key tiles
#define VTS 68    // u16 stride, valt [32 d][64 row']
#define WBS 24    // u16 stride, softmax weight tiles

using short8 = __attribute__((ext_vector_type(8))) short;
using float4f = __attribute__((ext_vector_type(4))) float;
#define MFMA16(a, b, c) __builtin_amdgcn_mfma_f32_16x16x32_bf16((a), (b), (c), 0, 0, 0)

__device__ __forceinline__ float bf2f(u16 u) { union { u32 i; float f; } v; v.i = ((u32)u) << 16; return v.f; }
__device__ __forceinline__ float lo2f(u32 w) { union { u32 i; float f; } v; v.i = w << 16; return v.f; }
__device__ __forceinline__ float hi2f(u32 w) { union { u32 i; float f; } v; v.i = w & 0xffff0000u; return v.f; }
__device__ __forceinline__ u16 f2bf(float f) {
  union { float f; u32 i; } v; v.f = f;
  u32 x = v.i;
  x += 0x7fffu + ((x >> 16) & 1u);   // RNE
  return (u16)(x >> 16);
}
__device__ __forceinline__ float lrelu(float x) { return x > 0.f ? x : 0.01f * x; }
__device__ __forceinline__ float ldin(const void* p, size_t i, bool bf) {
  return bf ? bf2f(((const u16*)p)[i]) : ((const float*)p)[i];
}
__device__ __forceinline__ u16 ldbf(const void* p, size_t i, bool bf) {
  return bf ? ((const u16*)p)[i] : f2bf(((const float*)p)[i]);
}
__device__ __forceinline__ short8 lds_s8(const u16* p) {   // 16B LDS load, 4B-aligned ok
  union { short8 v; u32 u[4]; } t;
  const u32* q = (const u32*)p;
  t.u[0] = q[0]; t.u[1] = q[1]; t.u[2] = q[2]; t.u[3] = q[3];
  return t.v;
}

// ---------------- K1: BN stats + folded dtype detect (proven round 6) ----------------
__global__ __launch_bounds__(256) void k_stats(const void* __restrict__ s, const void* __restrict__ a,
                                               int* __restrict__ flag, float* __restrict__ part) {
  __shared__ float S0[256], Q0[256], S1[256], Q1[256];
  __shared__ int cnt[2];
  int tid = threadIdx.x;
  if (tid < 2) cnt[tid] = 0;
  __syncthreads();
  {
    u32 wv = ((const u32*)s)[tid];
    u32 lo = wv & 0xffffu, e = (lo >> 7) & 0xffu;
    if (lo == 0u || lo == 0x8000u) atomicAdd(&cnt[1], 1);
    else if (e < 0x70u || e > 0x8fu) atomicAdd(&cnt[0], 1);
  }
  __syncthreads();
  bool bf = !(cnt[0] >= 64 || cnt[1] >= 192);
  if (blockIdx.x == 0 && tid == 0) *flag = bf ? 1 : 0;
  int blk = blockIdx.x, n = blk >> 5, c = blk & 31, b0 = c << 9;
  {
    int f2 = tid & 31, rg = tid >> 5;
    float s0 = 0.f, s1 = 0.f, q0 = 0.f, q1 = 0.f;
    for (int i = 0; i < 64; i++) {
      int b = b0 + rg + 8 * i;
      float x0, x1;
      if (bf) { u32 wv = ((const u32*)s)[((size_t)n * BATCH + b) * 32 + f2]; x0 = lo2f(wv); x1 = hi2f(wv); }
      else { const float* sf = (const float*)s + ((size_t)n * BATCH + b) * 64 + 2 * f2; x0 = sf[0]; x1 = sf[1]; }
      s0 += x0; q0 += x0 * x0; s1 += x1; q1 += x1 * x1;
    }
    S0[tid] = s0; Q0[tid] = q0; S1[tid] = s1; Q1[tid] = q1;
  }
  __syncthreads();
  if (tid < 64) {
    int f2 = tid >> 1, odd = tid & 1;
    float S = 0.f, Q = 0.f;
    for (int rg = 0; rg < 8; rg++) {
      int ix = rg * 32 + f2;
      S += odd ? S1[ix] : S0[ix];
      Q += odd ? Q1[ix] : Q0[ix];
    }
    float* p = part + ((size_t)blk * IND + tid) * 2;
    p[0] = S; p[1] = Q;
  }
  __syncthreads();
  {
    int f2 = tid & 7, rg = tid >> 3;
    float s0 = 0.f, s1 = 0.f, q0 = 0.f, q1 = 0.f;
    for (int i = 0; i < 16; i++) {
      int b = b0 + rg + 32 * i;
      float x0, x1;
      if (bf) { u32 wv = ((const u32*)a)[((size_t)n * BATCH + b) * 8 + f2]; x0 = lo2f(wv); x1 = hi2f(wv); }
      else { const float* af = (const float*)a + ((size_t)n * BATCH + b) * 16 + 2 * f2; x0 = af[0]; x1 = af[1]; }
      s0 += x0; q0 += x0 * x0; s1 += x1; q1 += x1 * x1;
    }
    S0[tid] = s0; Q0[tid] = q0; S1[tid] = s1; Q1[tid] = q1;
  }
  __syncthreads();
  if (tid < 16) {
    int f2 = tid >> 1, odd = tid & 1;
    float S = 0.f, Q = 0.f;
    for (int rg = 0; rg < 32; rg++) {
      int ix = rg * 8 + f2;
      S += odd ? S1[ix] : S0[ix];
      Q += odd ? Q1[ix] : Q0[ix];
    }
    float* p = part + ((size_t)blk * IND + SD + tid) * 2;
    p[0] = S; p[1] = Q;
  }
}

// ---------------- K2: weight prep + folded mst finalize (block 60) ----------------
__global__ __launch_bounds__(256) void k_wprep(
    const void* __restrict__ Wsa, const void* __restrict__ Wse,
    const void* __restrict__ Wsl, const void* __restrict__ Wk, const void* __restrict__ Wv,
    const void* __restrict__ Wc1, const int* __restrict__ flag, const float* __restrict__ part,
    u16* __restrict__ Wsa_t, u16* __restrict__ Wse_t, u16* __restrict__ Wp_t, u16* __restrict__ Wc1t,
    float* __restrict__ msts) {
  __shared__ u16 T[80 * 130];
  bool bf = (*flag != 0);
  int tid = threadIdx.x;
  int blk = blockIdx.x;
  if (blk < 32) {                       // Wc1 [n][256][128] -> Wc1t [n][128][256]
    int n = blk >> 2, k0 = (blk & 3) * 64;
    for (int i = tid; i < 64 * 128; i += 256) {
      int kr = i >> 7, cc = i & 127;
      T[kr * 130 + cc] = ldbf(Wc1, ((size_t)n * 256 + k0 + kr) * 128 + cc, bf);
    }
    __syncthreads();
    for (int i = tid; i < 128 * 64; i += 256) {
      int col = i >> 6, kk = i & 63;
      Wc1t[((size_t)n * 128 + col) * 256 + k0 + kk] = T[kk * 130 + col];
    }
  } else if (blk < 40) {                // Wsa -> Wsa_t
    int n = blk - 32;
    for (int i = tid; i < 80 * 128; i += 256) {
      int kr = i >> 7, cc = i & 127;
      T[kr * 130 + cc] = ldbf(Wsa, ((size_t)n * IND + kr) * 128 + cc, bf);
    }
    __syncthreads();
    for (int i = tid; i < 128 * KP3; i += 256) {
      int col = i / KP3, k = i - col * KP3;
      Wsa_t[((size_t)n * 128 + col) * KP3 + k] = (k < IND) ? T[k * 130 + col] : (u16)0;
    }
  } else if (blk < 48) {                // Wse -> Wse_t
    int n = blk - 40;
    for (int i = tid; i < 64 * 128; i += 256) {
      int kr = i >> 7, cc = i & 127;
      T[kr * 130 + cc] = ldbf(Wse, ((size_t)n * SD + kr) * 128 + cc, bf);
    }
    __syncthreads();
    for (int i = tid; i < 128 * KPS; i += 256) {
      int col = i / KPS, k = i - col * KPS;
      Wse_t[((size_t)n * 128 + col) * KPS + k] = (k < SD) ? T[k * 130 + col] : (u16)0;
    }
  } else if (blk < 60) {                // Wp -> Wp_t
    int pm = blk - 48, p = pm / 3, mat = pm - 3 * p;
    const void* W = (mat == 0) ? Wsl : (mat == 1) ? Wk : Wv;
    for (int i = tid; i < 128 * 32; i += 256) {
      int kr = i >> 5, d = i & 31;
      T[kr * 34 + d] = ldbf(W, ((size_t)p * HID + kr) * ATT + d, bf);
    }
    __syncthreads();
    for (int i = tid; i < 32 * KP; i += 256) {
      int d = i / KP, k = i - d * KP;
      Wp_t[(((size_t)p * 3 + mat) * ATT + d) * KP + k] = (k < HID) ? T[k * 34 + d] : (u16)0;
    }
  } else {                              // mst finalize: part -> msts[8][80][2]
    for (int i = tid; i < NA * IND; i += 256) {
      int n = i / IND, f = i - n * IND;
      float S = 0.f, Q = 0.f;
      for (int c = 0; c < 32; c++) {
        const float* pp = part + ((size_t)(n * 32 + c) * IND + f) * 2;
        S += pp[0]; Q += pp[1];
      }
      float mean = S * (1.f / BATCH);
      float var = Q * (1.f / BATCH) - mean * mean;
      msts[i * 2] = mean;
      msts[i * 2 + 1] = rsqrtf(var + EPS);
    }
  }
}

// ---------------- K3: MEGA-FUSED encoders + projections + attention ----------------
// block = 8 batch x 8 agents (rows agent-major: row = agent*8 + b).
// sanb normalized into XA (k 0..95); SE GEMM -> SEl (LDS) + SEo (global);
// E GEMM -> regs -> overwrite XA in place; per head: sel (from SEl) / key/val
// (from XA) -> MFMA logits -> shfl softmax -> MFMA weighted sum -> OT.
// Per-agent encoder weights: 16-row m-tile spans 2 agents -> run each MFMA with
// both agents' B, lane-select valid C rows (q<2 -> agent 2w, q>=2 -> 2w+1).
// LDS: XA 17408 + SEl 17408 + pool(selb|keyb, aliases mstl) 8704 + valt 4352
//      + wb 3072 + bvf 512 = 51456 B -> 3 blocks/CU.
__global__ __launch_bounds__(256) void k_fused(
    const void* __restrict__ s, const void* __restrict__ a,
    const u16* __restrict__ Wsa_t, const void* __restrict__ bsa,
    const u16* __restrict__ Wse_t, const void* __restrict__ bse,
    const u16* __restrict__ Wp_t, const void* __restrict__ bv_g,
    const float* __restrict__ msts, const int* __restrict__ flag,
    u16* __restrict__ SEo, u16* __restrict__ OT) {
  __shared__ __align__(16) u16 XA[64 * KP];
  __shared__ __align__(16) u16 SEl[64 * KP];
  __shared__ __align__(16) u16 pool[2 * 64 * SP];   // selb | keyb ; f32 mstl[1280] in phase A
  __shared__ __align__(16) u16 valt[ATT * VTS];
  __shared__ __align__(16) u16 wb[64 * WBS];
  __shared__ float bvf[HID];
  bool bf = (*flag != 0);
  int tid = threadIdx.x;
  int b0 = blockIdx.x * 8;
  int w = tid >> 6, lane = tid & 63, q = lane >> 4, rl = lane & 15;
  u16* selb = pool;
  u16* keyb = pool + 64 * SP;

  // ---- phase A: load mst, normalize-stage sanb into XA ----
  {
    float* mstl = (float*)pool;
    if (tid < HID) bvf[tid] = ldin(bv_g, tid, bf);
    for (int i = tid; i < NA * IND * 2; i += 256) mstl[i] = msts[i];
    __syncthreads();   // B0
    for (int i = tid; i < 64 * 32; i += 256) {       // s-part k 0..63
      int row = i >> 5, kp = i & 31;
      int n = row >> 3, b = row & 7;
      float x0, x1;
      if (bf) { u32 wv = ((const u32*)s)[((size_t)n * BATCH + b0 + b) * 32 + kp]; x0 = lo2f(wv); x1 = hi2f(wv); }
      else { const float* sf = (const float*)s + ((size_t)n * BATCH + b0 + b) * 64 + 2 * kp; x0 = sf[0]; x1 = sf[1]; }
      int k = 2 * kp;
      const float* ms = &mstl[(n * IND + k) * 2];
      u32 o = (u32)f2bf((x0 - ms[0]) * ms[1]) | ((u32)f2bf((x1 - ms[2]) * ms[3]) << 16);
      *(u32*)&XA[row * KP + k] = o;
    }
    for (int i = tid; i < 64 * 8; i += 256) {        // a-part k 64..79
      int row = i >> 3, kp = i & 7;
      int n = row >> 3, b = row & 7;
      float x0, x1;
      if (bf) { u32 wv = ((const u32*)a)[((size_t)n * BATCH + b0 + b) * 8 + kp]; x0 = lo2f(wv); x1 = hi2f(wv); }
      else { const float* af = (const float*)a + ((size_t)n * BATCH + b0 + b) * 16 + 2 * kp; x0 = af[0]; x1 = af[1]; }
      int k = SD + 2 * kp;
      const float* ms = &mstl[(n * IND + k) * 2];
      u32 o = (u32)f2bf((x0 - ms[0]) * ms[1]) | ((u32)f2bf((x1 - ms[2]) * ms[3]) << 16);
      *(u32*)&XA[row * KP + k] = o;
    }
    for (int i = tid; i < 64 * 8; i += 256) {        // zero k 80..95
      int row = i >> 3, c = i & 7;
      *(u32*)&XA[row * KP + IND + 2 * c] = 0u;
    }
  }
  __syncthreads();   // B1: sanb ready (mstl dead)

  // ---- phase B: SE = lrelu(bn(s) @ Wse[n] + bse[n]) -> SEl + SEo ----
  {
    float4f acc[2][8] = {};
    const u16* W0 = Wse_t + (size_t)(2 * w) * HID * KPS;
    const u16* W1 = Wse_t + (size_t)(2 * w + 1) * HID * KPS;
    #pragma unroll
    for (int kc = 0; kc < 2; kc++) {
      short8 af = *(const short8*)&XA[(w * 16 + rl) * KP + kc * 32 + q * 8];
      #pragma unroll
      for (int nt = 0; nt < 8; nt++) {
        short8 bb0 = *(const short8*)(W0 + (size_t)(nt * 16 + rl) * KPS + kc * 32 + q * 8);
        acc[0][nt] = MFMA16(af, bb0, acc[0][nt]);
        short8 bb1 = *(const short8*)(W1 + (size_t)(nt * 16 + rl) * KPS + kc * 32 + q * 8);
        acc[1][nt] = MFMA16(af, bb1, acc[1][nt]);
      }
    }
    int ag = 2 * w + (q >> 1);
    #pragma unroll
    for (int nt = 0; nt < 8; nt++) {
      int col = nt * 16 + rl;
      float bias = ldin(bse, ag * HID + col, bf);
      #pragma unroll
      for (int r = 0; r < 4; r++) {
        int row = w * 16 + q * 4 + r;
        float av = (q < 2) ? acc[0][nt][r] : acc[1][nt][r];
        u16 v = f2bf(lrelu(av + bias));
        SEl[row * KP + col] = v;
        SEo[((size_t)ag * BATCH + b0 + (row & 7)) * HID + col] = v;
      }
    }
  }
  // ---- phase C: E = lrelu(bn(sa) @ Wsa[n] + bsa[n]) -> regs -> XA in-place ----
  {
    float4f acc[2][8] = {};
    const u16* W0 = Wsa_t + (size_t)(2 * w) * HID * KP3;
    const u16* W1 = Wsa_t + (size_t)(2 * w + 1) * HID * KP3;
    #pragma unroll
    for (int kc = 0; kc < 3; kc++) {
      short8 af = *(const short8*)&XA[(w * 16 + rl) * KP + kc * 32 + q * 8];
      #pragma unroll
      for (int nt = 0; nt < 8; nt++) {
        short8 bb0 = *(const short8*)(W0 + (size_t)(nt * 16 + rl) * KP3 + kc * 32 + q * 8);
        acc[0][nt] = MFMA16(af, bb0, acc[0][nt]);
        short8 bb1 = *(const short8*)(W1 + (size_t)(nt * 16 + rl) * KP3 + kc * 32 + q * 8);
        acc[1][nt] = MFMA16(af, bb1, acc[1][nt]);
      }
    }
    __syncthreads();   // B2: all sanb reads done (SE + E); SEl visible
    int ag = 2 * w + (q >> 1);
    #pragma unroll
    for (int nt = 0; nt < 8; nt++) {
      int col = nt * 16 + rl;
      float bias = ldin(bsa, ag * HID + col, bf);
      #pragma unroll
      for (int r = 0; r < 4; r++) {
        int row = w * 16 + q * 4 + r;
        float av = (q < 2) ? acc[0][nt][r] : acc[1][nt][r];
        XA[row * KP + col] = f2bf(lrelu(av + bias));
      }
    }
  }
  __syncthreads();   // B3: E (XA) visible

  // ---- phase D: per head: sel/key/val proj -> MFMA logits -> softmax -> weighted sum ----
  const float scale = 0.17677669529663687f;
  for (int p = 0; p < HEADS; p++) {
    const u16* WSel = Wp_t + (size_t)(p * 3 + 0) * ATT * KP;
    const u16* WK   = Wp_t + (size_t)(p * 3 + 1) * ATT * KP;
    const u16* WV   = Wp_t + (size_t)(p * 3 + 2) * ATT * KP;
    {  // sel = SE @ Wsel[p]  (weights shared across agents)
      float4f acs[2] = {};
      #pragma unroll
      for (int kc = 0; kc < 4; kc++) {
        short8 af = *(const short8*)&SEl[(w * 16 + rl) * KP + kc * 32 + q * 8];
        #pragma unroll
        for (int nt = 0; nt < 2; nt++) {
          short8 bb = *(const short8*)(WSel + (size_t)(nt * 16 + rl) * KP + kc * 32 + q * 8);
          acs[nt] = MFMA16(af, bb, acs[nt]);
        }
      }
      #pragma unroll
      for (int nt = 0; nt < 2; nt++)
        #pragma unroll
        for (int r = 0; r < 4; r++) {
          int m = w * 16 + q * 4 + r;
          int rowp = ((m & 7) << 3) | (m >> 3);   // b-major
          selb[rowp * SP + nt * 16 + rl] = f2bf(acs[nt][r]);
        }
    }
    {  // key = E @ Wk[p], val = lrelu(E @ Wv[p] + bv[p])
      float4f ak[2] = {}, av[2] = {};
      #pragma unroll
      for (int kc = 0; kc < 4; kc++) {
        short8 af = *(const short8*)&XA[(w * 16 + rl) * KP + kc * 32 + q * 8];
        #pragma unroll
        for (int nt = 0; nt < 2; nt++) {
          short8 bk = *(const short8*)(WK + (size_t)(nt * 16 + rl) * KP + kc * 32 + q * 8);
          ak[nt] = MFMA16(af, bk, ak[nt]);
          short8 bv8 = *(const short8*)(WV + (size_t)(nt * 16 + rl) * KP + kc * 32 + q * 8);
          av[nt] = MFMA16(af, bv8, av[nt]);
        }
      }
      #pragma unroll
      for (int nt = 0; nt < 2; nt++)
        #pragma unroll
        for (int r = 0; r < 4; r++) {
          int m = w * 16 + q * 4 + r;
          int rowp = ((m & 7) << 3) | (m >> 3);
          int d = nt * 16 + rl;
          keyb[rowp * SP + d] = f2bf(ak[nt][r]);
          valt[d * VTS + rowp] = f2bf(lrelu(av[nt][r] + bvf[p * ATT + d]));
        }
    }
    __syncthreads();   // B4: selb/keyb/valt visible
    {
      short8 sa = lds_s8(&selb[(w * 16 + rl) * SP + q * 8]);
      short8 kb = lds_s8(&keyb[(w * 16 + rl) * SP + q * 8]);
      float4f zc = {};
      float4f c = MFMA16(sa, kb, zc);
      int nn = rl;
      #pragma unroll
      for (int r = 0; r < 4; r++) {
        int row = q * 4 + r;
        float x = c[r] * scale;
        if (row == nn) x = -1e9f;                    // self-mask (same b, i==j)
        float mx = x;
        mx = fmaxf(mx, __shfl_xor(mx, 1));
        mx = fmaxf(mx, __shfl_xor(mx, 2));
        mx = fmaxf(mx, __shfl_xor(mx, 4));
        float e = __expf(x - mx);
        float ssum = e;
        ssum += __shfl_xor(ssum, 1);
        ssum += __shfl_xor(ssum, 2);
        ssum += __shfl_xor(ssum, 4);
        float wv = e / ssum;
        if ((row >> 3) != (nn >> 3)) wv = 0.f;       // zero cross-b junk
        wb[(w * 16 + row) * WBS + nn] = f2bf(wv);    // per-wave private rows
      }
      short8 aw;
      if (q < 2) aw = *(const short8*)&wb[(w * 16 + rl) * WBS + q * 8];
      else { short8 z = {}; aw = z; }
      float4f o[2] = {};
      #pragma unroll
      for (int nt = 0; nt < 2; nt++) {
        short8 bv8 = lds_s8(&valt[(nt * 16 + rl) * VTS + w * 16 + (q & 1) * 8]);
        o[nt] = MFMA16(aw, bv8, o[nt]);
      }
      #pragma unroll
      for (int nt = 0; nt < 2; nt++)
        #pragma unroll
        for (int r = 0; r < 4; r++) {
          int row = q * 4 + r;
          int b = 2 * w + (row >> 3), i = row & 7;
          OT[((size_t)i * BATCH + b0 + b) * HID + p * ATT + nt * 16 + rl] = f2bf(o[nt][r]);
        }
    }
    __syncthreads();   // B5: scratch reads done before next head's writes
  }
}

// ---------------- K4: critic MFMA GEMM + argmax gather (proven round 6) ----------------
__global__ __launch_bounds__(256) void k_critic(
    const u16* __restrict__ SEi, const u16* __restrict__ OT, const void* __restrict__ a_g,
    const u16* __restrict__ Wc1t, const void* __restrict__ bc1_g,
    const void* __restrict__ Wc2_g, const void* __restrict__ bc2_g,
    const int* __restrict__ flag, void* __restrict__ qo) {
  __shared__ __align__(16) u16 Xt[128 * KP];
  __shared__ float wc2f[HID * AD];
  __shared__ float bc1f[HID];
  __shared__ int amax[128];
  bool bf = (*flag != 0);
  int tid = threadIdx.x;
  int n = blockIdx.y;
  int b0 = blockIdx.x * 128;
  int w = tid >> 6, lane = tid & 63, q = lane >> 4, rl = lane & 15;
  if (tid < HID) bc1f[tid] = ldin(bc1_g, n * HID + tid, bf);
  const u16* WT = Wc1t + (size_t)n * HID * 256;

  float4f acc[2][8] = {};
  for (int ph = 0; ph < 2; ph++) {
    const u32* su = (const u32*)(ph == 0 ? SEi : OT);
    for (int idx = tid; idx < 128 * 64; idx += 256) {
      int row = idx >> 6, c = idx & 63;
      ((u32*)&Xt[row * KP])[c] = su[((size_t)n * BATCH + b0 + row) * 64 + c];
    }
    __syncthreads();
    #pragma unroll
    for (int kc = 0; kc < 4; kc++) {
      int ko = ph * HID + kc * 32;
      short8 a0 = *(const short8*)&Xt[((2 * w) * 16 + rl) * KP + kc * 32 + q * 8];
      short8 a1 = *(const short8*)&Xt[((2 * w + 1) * 16 + rl) * KP + kc * 32 + q * 8];
      #pragma unroll
      for (int nt = 0; nt < 8; nt++) {
        short8 bb = *(const short8*)(WT + (size_t)(nt * 16 + rl) * 256 + ko + q * 8);
        acc[0][nt] = MFMA16(a0, bb, acc[0][nt]);
        acc[1][nt] = MFMA16(a1, bb, acc[1][nt]);
      }
    }
    __syncthreads();
  }
  u16* ht = Xt;
  #pragma unroll
  for (int mi = 0; mi < 2; mi++)
    #pragma unroll
    for (int nt = 0; nt < 8; nt++)
      #pragma unroll
      for (int r = 0; r < 4; r++) {
        int row = (2 * w + mi) * 16 + q * 4 + r, col = nt * 16 + rl;
        ht[row * KP + col] = f2bf(lrelu(acc[mi][nt][r] + bc1f[col]));
      }
  for (int idx = tid; idx < HID * AD; idx += 256)
    wc2f[idx] = ldin(Wc2_g, (size_t)n * HID * AD + idx, bf);
  if (tid < 128) {
    size_t base = ((size_t)n * BATCH + b0 + tid) * AD;
    float best = ldin(a_g, base, bf); int bi = 0;
    for (int o = 1; o < AD; o++) {
      float v = ldin(a_g, base + o, bf);
      if (v > best) { best = v; bi = o; }   // strict > = first-max
    }
    amax[tid] = bi;
  }
  __syncthreads();
  {
    int b = tid >> 1, half = tid & 1;
    int col = amax[b];
    float acq = 0.f;
    const u16* hr = &ht[b * KP + half * 64];
    #pragma unroll
    for (int k = 0; k < 64; k++)
      acq = fmaf(bf2f(hr[k]), wc2f[(half * 64 + k) * AD + col], acq);
    acq += __shfl_xor(acq, 1);
    if (half == 0) {
      float v = acq + ldin(bc2_g, n * AD + col, bf);
      size_t oidx = (size_t)n * BATCH + b0 + b;
      if (bf) ((u16*)qo)[oidx] = f2bf(v);
      else    ((float*)qo)[oidx] = v;
    }
  }
}

extern "C" void kernel_launch(void* const* d_in, const int* in_sizes, int n_in,
                              void* d_out, int out_size, void* d_ws, size_t ws_size,
                              hipStream_t stream) {
  const void* s   = d_in[0];
  const void* a   = d_in[1];
  const void* Wsa = d_in[2];
  const void* bsa = d_in[3];
  const void* Wse = d_in[4];
  const void* bse = d_in[5];
  const void* Wk  = d_in[6];
  const void* Wsl = d_in[7];
  const void* Wv  = d_in[8];
  const void* bv  = d_in[9];
  const void* Wc1 = d_in[10];
  const void* bc1 = d_in[11];
  const void* Wc2 = d_in[12];
  const void* bc2 = d_in[13];

  char* ws = (char*)d_ws;
  int*   flag  = (int*)ws;
  float* part  = (float*)(ws + 256);
  float* msts  = (float*)(ws + 164096);
  u16*   Wsa_t = (u16*)(ws + 169216);
  u16*   Wse_t = (u16*)(ws + 382208);
  u16*   Wp_t  = (u16*)(ws + 529664);
  u16*   Wc1t  = (u16*)(ws + 634112);
  u16*   SEb   = (u16*)(ws + 1158400 + 33554432ull);
  u16*   OT    = (u16*)(ws + 1158400 + 2ull * 33554432ull);

  k_stats<<<256, 256, 0, stream>>>(s, a, flag, part);
  k_wprep<<<61, 256, 0, stream>>>(Wsa, Wse, Wsl, Wk, Wv, Wc1, flag, part,
                                  Wsa_t, Wse_t, Wp_t, Wc1t, msts);
  k_fused<<<BATCH / 8, 256, 0, stream>>>(s, a, Wsa_t, bsa, Wse_t, bse, Wp_t, bv,
                                         msts, flag, SEb, OT);
  k_critic<<<dim3(BATCH / 128, NA), 256, 0, stream>>>(SEb, OT, a, Wc1t, bc1, Wc2, bc2, flag, d_out);
}

// Round 8
// 310.755 us; speedup vs baseline: 1.0815x; 1.0815x over previous
//
#include <hip/hip_runtime.h>

// Attention_Critic on MI355X — round 8: revert to round-6 5-kernel structure
// (fusion regressed: latency-bound, not traffic-bound), plus:
//  - pattn5: sel held in registers (LDS 47104->34048, 3->4 blocks/CU)
//  - packed u32 stores (shfl col-pair packing) in enc2 + pattn5 epilogues
//  - critic: bf16 Wc2 staging (LDS 44032->39936, 3->4 blocks/CU)
//
// ws layout (bytes):
//   [0,256)        int flag (1 = bf16 inputs, 0 = f32)
//   [256,+163840)  stats partials f32 [8][32][80][2]
//   [169216,...)   Wsa_t bf16 [8][128 col][104 k]
//   [382208,...)   Wse_t bf16 [8][128 col][72 k]
//   [529664,...)   Wp_t  bf16 [4 p][3 mat][32 d][136 k]  (mat 0=sel,1=key,2=val)
//   [634112,...)   Wc1t  bf16 [8][128 col][256 k]
//   [1158400,+32M) E   bf16 [8][16384][128]
//   [+32M,+64M)    SE  bf16 [8][16384][128]
//   [+64M,+96M)    OT  bf16 [8][16384][128]

typedef unsigned short u16;
typedef unsigned int u32;

#define NA 8
#define BATCH 16384
#define SD 64
#define AD 16
#define IND 80
#define HID 128
#define HEADS 4
#define ATT 32
#define EPS 1e-5f
#define KP 136    // u16 stride, 128-k tiles
#define KP3 104   // u16 stride, 96-k tiles (Wsa_t)
#define KPS 72    // u16 stride, 64-k tiles (Wse_t)
#define SP 34     // u16 stride, 32-wide sel/key tiles
#define VTS 68    // u16 stride, valt [32 d][64 row']
#define WBS 24    // u16 stride, softmax weight tiles

using short8 = __attribute__((ext_vector_type(8))) short;
using float4f = __attribute__((ext_vector_type(4))) float;
#define MFMA16(a, b, c) __builtin_amdgcn_mfma_f32_16x16x32_bf16((a), (b), (c), 0, 0, 0)

__device__ __forceinline__ float bf2f(u16 u) { union { u32 i; float f; } v; v.i = ((u32)u) << 16; return v.f; }
__device__ __forceinline__ float lo2f(u32 w) { union { u32 i; float f; } v; v.i = w << 16; return v.f; }
__device__ __forceinline__ float hi2f(u32 w) { union { u32 i; float f; } v; v.i = w & 0xffff0000u; return v.f; }
__device__ __forceinline__ u16 f2bf(float f) {
  union { float f; u32 i; } v; v.f = f;
  u32 x = v.i;
  x += 0x7fffu + ((x >> 16) & 1u);   // RNE
  return (u16)(x >> 16);
}
__device__ __forceinline__ float lrelu(float x) { return x > 0.f ? x : 0.01f * x; }
__device__ __forceinline__ float ldin(const void* p, size_t i, bool bf) {
  return bf ? bf2f(((const u16*)p)[i]) : ((const float*)p)[i];
}
__device__ __forceinline__ u16 ldbf(const void* p, size_t i, bool bf) {
  return bf ? ((const u16*)p)[i] : f2bf(((const float*)p)[i]);
}
__device__ __forceinline__ short8 lds_s8(const u16* p) {   // 16B LDS load, 4B-aligned ok
  union { short8 v; u32 u[4]; } t;
  const u32* q = (const u32*)p;
  t.u[0] = q[0]; t.u[1] = q[1]; t.u[2] = q[2]; t.u[3] = q[3];
  return t.v;
}

// ---------------- K1: BN stats + folded dtype detect (proven round 6) ----------------
__global__ __launch_bounds__(256) void k_stats(const void* __restrict__ s, const void* __restrict__ a,
                                               int* __restrict__ flag, float* __restrict__ part) {
  __shared__ float S0[256], Q0[256], S1[256], Q1[256];
  __shared__ int cnt[2];
  int tid = threadIdx.x;
  if (tid < 2) cnt[tid] = 0;
  __syncthreads();
  {
    u32 wv = ((const u32*)s)[tid];
    u32 lo = wv & 0xffffu, e = (lo >> 7) & 0xffu;
    if (lo == 0u || lo == 0x8000u) atomicAdd(&cnt[1], 1);
    else if (e < 0x70u || e > 0x8fu) atomicAdd(&cnt[0], 1);
  }
  __syncthreads();
  bool bf = !(cnt[0] >= 64 || cnt[1] >= 192);
  if (blockIdx.x == 0 && tid == 0) *flag = bf ? 1 : 0;
  int blk = blockIdx.x, n = blk >> 5, c = blk & 31, b0 = c << 9;
  {
    int f2 = tid & 31, rg = tid >> 5;
    float s0 = 0.f, s1 = 0.f, q0 = 0.f, q1 = 0.f;
    for (int i = 0; i < 64; i++) {
      int b = b0 + rg + 8 * i;
      float x0, x1;
      if (bf) { u32 wv = ((const u32*)s)[((size_t)n * BATCH + b) * 32 + f2]; x0 = lo2f(wv); x1 = hi2f(wv); }
      else { const float* sf = (const float*)s + ((size_t)n * BATCH + b) * 64 + 2 * f2; x0 = sf[0]; x1 = sf[1]; }
      s0 += x0; q0 += x0 * x0; s1 += x1; q1 += x1 * x1;
    }
    S0[tid] = s0; Q0[tid] = q0; S1[tid] = s1; Q1[tid] = q1;
  }
  __syncthreads();
  if (tid < 64) {
    int f2 = tid >> 1, odd = tid & 1;
    float S = 0.f, Q = 0.f;
    for (int rg = 0; rg < 8; rg++) {
      int ix = rg * 32 + f2;
      S += odd ? S1[ix] : S0[ix];
      Q += odd ? Q1[ix] : Q0[ix];
    }
    float* p = part + ((size_t)blk * IND + tid) * 2;
    p[0] = S; p[1] = Q;
  }
  __syncthreads();
  {
    int f2 = tid & 7, rg = tid >> 3;
    float s0 = 0.f, s1 = 0.f, q0 = 0.f, q1 = 0.f;
    for (int i = 0; i < 16; i++) {
      int b = b0 + rg + 32 * i;
      float x0, x1;
      if (bf) { u32 wv = ((const u32*)a)[((size_t)n * BATCH + b) * 8 + f2]; x0 = lo2f(wv); x1 = hi2f(wv); }
      else { const float* af = (const float*)a + ((size_t)n * BATCH + b) * 16 + 2 * f2; x0 = af[0]; x1 = af[1]; }
      s0 += x0; q0 += x0 * x0; s1 += x1; q1 += x1 * x1;
    }
    S0[tid] = s0; Q0[tid] = q0; S1[tid] = s1; Q1[tid] = q1;
  }
  __syncthreads();
  if (tid < 16) {
    int f2 = tid >> 1, odd = tid & 1;
    float S = 0.f, Q = 0.f;
    for (int rg = 0; rg < 32; rg++) {
      int ix = rg * 8 + f2;
      S += odd ? S1[ix] : S0[ix];
      Q += odd ? Q1[ix] : Q0[ix];
    }
    float* p = part + ((size_t)blk * IND + SD + tid) * 2;
    p[0] = S; p[1] = Q;
  }
}

// ---------------- K2: weight prep — coalesced tiled LDS transpose (proven round 6) ----------------
__global__ __launch_bounds__(256) void k_wprep(
    const void* __restrict__ Wsa, const void* __restrict__ Wse,
    const void* __restrict__ Wsl, const void* __restrict__ Wk, const void* __restrict__ Wv,
    const void* __restrict__ Wc1, const int* __restrict__ flag,
    u16* __restrict__ Wsa_t, u16* __restrict__ Wse_t, u16* __restrict__ Wp_t, u16* __restrict__ Wc1t) {
  __shared__ u16 T[80 * 130];
  bool bf = (*flag != 0);
  int tid = threadIdx.x;
  int blk = blockIdx.x;
  if (blk < 32) {                       // Wc1 [n][256][128] -> Wc1t [n][128][256]
    int n = blk >> 2, k0 = (blk & 3) * 64;
    for (int i = tid; i < 64 * 128; i += 256) {
      int kr = i >> 7, cc = i & 127;
      T[kr * 130 + cc] = ldbf(Wc1, ((size_t)n * 256 + k0 + kr) * 128 + cc, bf);
    }
    __syncthreads();
    for (int i = tid; i < 128 * 64; i += 256) {
      int col = i >> 6, kk = i & 63;
      Wc1t[((size_t)n * 128 + col) * 256 + k0 + kk] = T[kk * 130 + col];
    }
  } else if (blk < 40) {                // Wsa -> Wsa_t
    int n = blk - 32;
    for (int i = tid; i < 80 * 128; i += 256) {
      int kr = i >> 7, cc = i & 127;
      T[kr * 130 + cc] = ldbf(Wsa, ((size_t)n * IND + kr) * 128 + cc, bf);
    }
    __syncthreads();
    for (int i = tid; i < 128 * KP3; i += 256) {
      int col = i / KP3, k = i - col * KP3;
      Wsa_t[((size_t)n * 128 + col) * KP3 + k] = (k < IND) ? T[k * 130 + col] : (u16)0;
    }
  } else if (blk < 48) {                // Wse -> Wse_t
    int n = blk - 40;
    for (int i = tid; i < 64 * 128; i += 256) {
      int kr = i >> 7, cc = i & 127;
      T[kr * 130 + cc] = ldbf(Wse, ((size_t)n * SD + kr) * 128 + cc, bf);
    }
    __syncthreads();
    for (int i = tid; i < 128 * KPS; i += 256) {
      int col = i / KPS, k = i - col * KPS;
      Wse_t[((size_t)n * 128 + col) * KPS + k] = (k < SD) ? T[k * 130 + col] : (u16)0;
    }
  } else {                              // Wp -> Wp_t
    int pm = blk - 48, p = pm / 3, mat = pm - 3 * p;
    const void* W = (mat == 0) ? Wsl : (mat == 1) ? Wk : Wv;
    for (int i = tid; i < 128 * 32; i += 256) {
      int kr = i >> 5, d = i & 31;
      T[kr * 34 + d] = ldbf(W, ((size_t)p * HID + kr) * ATT + d, bf);
    }
    __syncthreads();
    for (int i = tid; i < 32 * KP; i += 256) {
      int d = i / KP, k = i - d * KP;
      Wp_t[(((size_t)p * 3 + mat) * ATT + d) * KP + k] = (k < HID) ? T[k * 34 + d] : (u16)0;
    }
  }
}

// ---------------- K3: MFMA encoders, packed u32 epilogue stores ----------------
// LDS: sanb 26624 + mst 640 + biases 1024 = 28288 B (5 blocks/CU)
__global__ __launch_bounds__(256) void k_enc2(const void* __restrict__ s, const void* __restrict__ a,
    const u16* __restrict__ Wsa_t, const void* __restrict__ bsa,
    const u16* __restrict__ Wse_t, const void* __restrict__ bse,
    const float* __restrict__ part, const int* __restrict__ flag,
    u16* __restrict__ E, u16* __restrict__ SEo) {
  __shared__ __align__(16) u16 sanb[128 * KP3];
  __shared__ float mst[IND * 2];
  __shared__ float bsaf[HID], bsef[HID];
  bool bf = (*flag != 0);
  int tid = threadIdx.x;
  int n = blockIdx.y;
  int b0 = blockIdx.x * 128;
  int w = tid >> 6, lane = tid & 63, q = lane >> 4, rl = lane & 15;
  if (tid < HID) { bsaf[tid] = ldin(bsa, n * HID + tid, bf); bsef[tid] = ldin(bse, n * HID + tid, bf); }
  if (tid < IND) {   // folded stats finalize
    float S = 0.f, Q = 0.f;
    for (int c = 0; c < 32; c++) {
      const float* pp = part + ((size_t)(n * 32 + c) * IND + tid) * 2;
      S += pp[0]; Q += pp[1];
    }
    float mean = S * (1.f / BATCH);
    float var = Q * (1.f / BATCH) - mean * mean;
    mst[tid * 2] = mean;
    mst[tid * 2 + 1] = rsqrtf(var + EPS);
  }
  __syncthreads();
  for (int i = tid; i < 128 * 32; i += 256) {          // s-part k 0..63
    int row = i >> 5, kp = i & 31;
    float x0, x1;
    if (bf) { u32 wv = ((const u32*)s)[((size_t)n * BATCH + b0 + row) * 32 + kp]; x0 = lo2f(wv); x1 = hi2f(wv); }
    else { const float* sf = (const float*)s + ((size_t)n * BATCH + b0 + row) * 64 + 2 * kp; x0 = sf[0]; x1 = sf[1]; }
    int k = 2 * kp;
    u32 o = (u32)f2bf((x0 - mst[k * 2]) * mst[k * 2 + 1]) |
            ((u32)f2bf((x1 - mst[k * 2 + 2]) * mst[k * 2 + 3]) << 16);
    *(u32*)&sanb[row * KP3 + k] = o;
  }
  for (int i = tid; i < 128 * 8; i += 256) {           // a-part k 64..79
    int row = i >> 3, kp = i & 7;
    float x0, x1;
    if (bf) { u32 wv = ((const u32*)a)[((size_t)n * BATCH + b0 + row) * 8 + kp]; x0 = lo2f(wv); x1 = hi2f(wv); }
    else { const float* af = (const float*)a + ((size_t)n * BATCH + b0 + row) * 16 + 2 * kp; x0 = af[0]; x1 = af[1]; }
    int k = SD + 2 * kp;
    u32 o = (u32)f2bf((x0 - mst[k * 2]) * mst[k * 2 + 1]) |
            ((u32)f2bf((x1 - mst[k * 2 + 2]) * mst[k * 2 + 3]) << 16);
    *(u32*)&sanb[row * KP3 + k] = o;
  }
  for (int i = tid; i < 128 * 12; i += 256) {          // zero pad k 80..103
    int row = i / 12, c2 = i - row * 12;
    *(u32*)&sanb[row * KP3 + IND + 2 * c2] = 0u;
  }
  __syncthreads();
  const u16* WA = Wsa_t + (size_t)n * HID * KP3;
  const u16* WS = Wse_t + (size_t)n * HID * KPS;
  int r0 = (rl & 1) * 2;                                // even lanes store r 0,1; odd 2,3
  {  // E = lrelu(bn(sa) @ Wsa + bsa), K=96
    float4f acc[2][8] = {};
    #pragma unroll
    for (int kc = 0; kc < 3; kc++) {
      short8 a0 = *(const short8*)&sanb[((2 * w) * 16 + rl) * KP3 + kc * 32 + q * 8];
      short8 a1 = *(const short8*)&sanb[((2 * w + 1) * 16 + rl) * KP3 + kc * 32 + q * 8];
      #pragma unroll
      for (int nt = 0; nt < 8; nt++) {
        short8 bb = *(const short8*)(WA + (size_t)(nt * 16 + rl) * KP3 + kc * 32 + q * 8);
        acc[0][nt] = MFMA16(a0, bb, acc[0][nt]);
        acc[1][nt] = MFMA16(a1, bb, acc[1][nt]);
      }
    }
    #pragma unroll
    for (int mi = 0; mi < 2; mi++)
      #pragma unroll
      for (int nt = 0; nt < 8; nt++) {
        float bias = bsaf[nt * 16 + rl];
        u32 pk[4];
        #pragma unroll
        for (int r = 0; r < 4; r++) {
          u32 v32 = f2bf(lrelu(acc[mi][nt][r] + bias));
          u32 o32 = __shfl_xor(v32, 1);
          pk[r] = (rl & 1) ? (o32 | (v32 << 16)) : (v32 | (o32 << 16));
        }
        u32 pa = (rl & 1) ? pk[2] : pk[0];
        u32 pb = (rl & 1) ? pk[3] : pk[1];
        int colp = (nt * 16 + (rl & ~1)) >> 1;
        int rowa = (2 * w + mi) * 16 + q * 4 + r0;
        ((u32*)E)[((size_t)n * BATCH + b0 + rowa) * 64 + colp] = pa;
        ((u32*)E)[((size_t)n * BATCH + b0 + rowa + 1) * 64 + colp] = pb;
      }
  }
  {  // SE = lrelu(bn(s) @ Wse + bse), K=64
    float4f acc[2][8] = {};
    #pragma unroll
    for (int kc = 0; kc < 2; kc++) {
      short8 a0 = *(const short8*)&sanb[((2 * w) * 16 + rl) * KP3 + kc * 32 + q * 8];
      short8 a1 = *(const short8*)&sanb[((2 * w + 1) * 16 + rl) * KP3 + kc * 32 + q * 8];
      #pragma unroll
      for (int nt = 0; nt < 8; nt++) {
        short8 bb = *(const short8*)(WS + (size_t)(nt * 16 + rl) * KPS + kc * 32 + q * 8);
        acc[0][nt] = MFMA16(a0, bb, acc[0][nt]);
        acc[1][nt] = MFMA16(a1, bb, acc[1][nt]);
      }
    }
    #pragma unroll
    for (int mi = 0; mi < 2; mi++)
      #pragma unroll
      for (int nt = 0; nt < 8; nt++) {
        float bias = bsef[nt * 16 + rl];
        u32 pk[4];
        #pragma unroll
        for (int r = 0; r < 4; r++) {
          u32 v32 = f2bf(lrelu(acc[mi][nt][r] + bias));
          u32 o32 = __shfl_xor(v32, 1);
          pk[r] = (rl & 1) ? (o32 | (v32 << 16)) : (v32 | (o32 << 16));
        }
        u32 pa = (rl & 1) ? pk[2] : pk[0];
        u32 pb = (rl & 1) ? pk[3] : pk[1];
        int colp = (nt * 16 + (rl & ~1)) >> 1;
        int rowa = (2 * w + mi) * 16 + q * 4 + r0;
        ((u32*)SEo)[((size_t)n * BATCH + b0 + rowa) * 64 + colp] = pa;
        ((u32*)SEo)[((size_t)n * BATCH + b0 + rowa + 1) * 64 + colp] = pb;
      }
  }
}

// ---------------- K4: projections + full-MFMA attention, sel-in-registers ----------------
// LDS: X 17408 + selb 4352 + keyb 4352 + valt 4352 + wb 3072 + bvf 512 = 34048 B (4 blocks/CU)
__global__ __launch_bounds__(256) void k_pattn5(
    const u16* __restrict__ E, const u16* __restrict__ SEi,
    const u16* __restrict__ Wp_t, const void* __restrict__ bv_g,
    const int* __restrict__ flag, u16* __restrict__ OT) {
  __shared__ __align__(16) u16 X[64 * KP];
  __shared__ __align__(16) u16 selb[64 * SP];
  __shared__ __align__(16) u16 keyb[64 * SP];
  __shared__ __align__(16) u16 valt[ATT * VTS];
  __shared__ __align__(16) u16 wb[64 * WBS];
  __shared__ float bvf[HID];
  bool bf = (*flag != 0);
  int tid = threadIdx.x;
  int b0 = blockIdx.x * 8;
  int w = tid >> 6, lane = tid & 63, q = lane >> 4, rl = lane & 15;
  if (tid < HID) bvf[tid] = ldin(bv_g, tid, bf);
  // stage X <- SE
  {
    const u32* su = (const u32*)SEi;
    for (int idx = tid; idx < 64 * 64; idx += 256) {
      int row = idx >> 6, c = idx & 63;
      ((u32*)&X[row * KP])[c] = su[(((size_t)(row >> 3)) * BATCH + b0 + (row & 7)) * 64 + c];
    }
  }
  __syncthreads();   // A
  // sel for all heads -> registers (bf16-packed)
  u32 selr[HEADS][2][2];
  #pragma unroll
  for (int p = 0; p < HEADS; p++) {
    const u16* WB = Wp_t + (size_t)(p * 3) * ATT * KP;
    float4f acs[2] = {};
    #pragma unroll
    for (int kc = 0; kc < 4; kc++) {
      short8 af = *(const short8*)&X[(w * 16 + rl) * KP + kc * 32 + q * 8];
      #pragma unroll
      for (int nt = 0; nt < 2; nt++) {
        short8 bb = *(const short8*)(WB + (size_t)(nt * 16 + rl) * KP + kc * 32 + q * 8);
        acs[nt] = MFMA16(af, bb, acs[nt]);
      }
    }
    #pragma unroll
    for (int nt = 0; nt < 2; nt++) {
      selr[p][nt][0] = (u32)f2bf(acs[nt][0]) | ((u32)f2bf(acs[nt][1]) << 16);
      selr[p][nt][1] = (u32)f2bf(acs[nt][2]) | ((u32)f2bf(acs[nt][3]) << 16);
    }
  }
  __syncthreads();   // B: all SE reads done
  // restage X <- E
  {
    const u32* su = (const u32*)E;
    for (int idx = tid; idx < 64 * 64; idx += 256) {
      int row = idx >> 6, c = idx & 63;
      ((u32*)&X[row * KP])[c] = su[(((size_t)(row >> 3)) * BATCH + b0 + (row & 7)) * 64 + c];
    }
  }
  __syncthreads();   // C
  const float scale = 0.17677669529663687f;
  #pragma unroll
  for (int p = 0; p < HEADS; p++) {
    // write this head's selb from registers (b-major transform)
    #pragma unroll
    for (int nt = 0; nt < 2; nt++)
      #pragma unroll
      for (int r = 0; r < 4; r++) {
        int m = w * 16 + q * 4 + r;
        int rowp = ((m & 7) << 3) | (m >> 3);
        u16 v = (u16)(selr[p][nt][r >> 1] >> ((r & 1) * 16));
        selb[rowp * SP + nt * 16 + rl] = v;
      }
    // key/val projection from X(E), B-frags direct from global
    const u16* WK = Wp_t + (size_t)(p * 3 + 1) * ATT * KP;
    const u16* WV = Wp_t + (size_t)(p * 3 + 2) * ATT * KP;
    {
      float4f ak[2] = {}, av[2] = {};
      #pragma unroll
      for (int kc = 0; kc < 4; kc++) {
        short8 af = *(const short8*)&X[(w * 16 + rl) * KP + kc * 32 + q * 8];
        #pragma unroll
        for (int nt = 0; nt < 2; nt++) {
          short8 bk = *(const short8*)(WK + (size_t)(nt * 16 + rl) * KP + kc * 32 + q * 8);
          ak[nt] = MFMA16(af, bk, ak[nt]);
          short8 bv8 = *(const short8*)(WV + (size_t)(nt * 16 + rl) * KP + kc * 32 + q * 8);
          av[nt] = MFMA16(af, bv8, av[nt]);
        }
      }
      #pragma unroll
      for (int nt = 0; nt < 2; nt++)
        #pragma unroll
        for (int r = 0; r < 4; r++) {
          int m = w * 16 + q * 4 + r;
          int rowp = ((m & 7) << 3) | (m >> 3);
          int d = nt * 16 + rl;
          keyb[rowp * SP + d] = f2bf(ak[nt][r]);
          valt[d * VTS + rowp] = f2bf(lrelu(av[nt][r] + bvf[p * ATT + d]));
        }
    }
    __syncthreads();   // D: selb/keyb/valt visible
    {
      short8 sa = lds_s8(&selb[(w * 16 + rl) * SP + q * 8]);
      short8 kb = lds_s8(&keyb[(w * 16 + rl) * SP + q * 8]);
      float4f zc = {};
      float4f c = MFMA16(sa, kb, zc);
      int nn = rl;
      #pragma unroll
      for (int r = 0; r < 4; r++) {
        int row = q * 4 + r;
        float x = c[r] * scale;
        if (row == nn) x = -1e9f;                    // self-mask (same b, i==j)
        float mx = x;
        mx = fmaxf(mx, __shfl_xor(mx, 1));
        mx = fmaxf(mx, __shfl_xor(mx, 2));
        mx = fmaxf(mx, __shfl_xor(mx, 4));
        float e = __expf(x - mx);
        float ssum = e;
        ssum += __shfl_xor(ssum, 1);
        ssum += __shfl_xor(ssum, 2);
        ssum += __shfl_xor(ssum, 4);
        float wv = e / ssum;
        if ((row >> 3) != (nn >> 3)) wv = 0.f;       // zero cross-b junk
        wb[(w * 16 + row) * WBS + nn] = f2bf(wv);    // wave-private rows
      }
      short8 aw;
      if (q < 2) aw = *(const short8*)&wb[(w * 16 + rl) * WBS + q * 8];
      else { short8 z = {}; aw = z; }
      float4f o[2] = {};
      #pragma unroll
      for (int nt = 0; nt < 2; nt++) {
        short8 bv8 = lds_s8(&valt[(nt * 16 + rl) * VTS + w * 16 + (q & 1) * 8]);
        o[nt] = MFMA16(aw, bv8, o[nt]);
      }
      // packed u32 OT stores (shfl col-pair packing; even lanes r 0,1 / odd r 2,3)
      int r0 = (rl & 1) * 2;
      #pragma unroll
      for (int nt = 0; nt < 2; nt++) {
        u32 pk[4];
        #pragma unroll
        for (int r = 0; r < 4; r++) {
          u32 v32 = f2bf(o[nt][r]);
          u32 o32 = __shfl_xor(v32, 1);
          pk[r] = (rl & 1) ? (o32 | (v32 << 16)) : (v32 | (o32 << 16));
        }
        u32 pa = (rl & 1) ? pk[2] : pk[0];
        u32 pb = (rl & 1) ? pk[3] : pk[1];
        int colp = p * 16 + nt * 8 + (rl >> 1);
        #pragma unroll
        for (int j = 0; j < 2; j++) {
          int row = q * 4 + r0 + j;
          int b = 2 * w + (row >> 3), i = row & 7;
          ((u32*)OT)[((size_t)i * BATCH + b0 + b) * 64 + colp] = j ? pb : pa;
        }
      }
    }
    __syncthreads();   // E_p: scratch reads done before next head's writes
  }
}

// ---------------- K5: critic MFMA GEMM + argmax gather (bf16 Wc2 staging) ----------------
// LDS: Xt 34816 + wc2h 4096 + bc1f 512 + amax 512 = 39936 B (4 blocks/CU)
__global__ __launch_bounds__(256) void k_critic(
    const u16* __restrict__ SEi, const u16* __restrict__ OT, const void* __restrict__ a_g,
    const u16* __restrict__ Wc1t, const void* __restrict__ bc1_g,
    const void* __restrict__ Wc2_g, const void* __restrict__ bc2_g,
    const int* __restrict__ flag, void* __restrict__ qo) {
  __shared__ __align__(16) u16 Xt[128 * KP];   // input rows; reused as ht
  __shared__ u16 wc2h[HID * AD];
  __shared__ float bc1f[HID];
  __shared__ int amax[128];
  bool bf = (*flag != 0);
  int tid = threadIdx.x;
  int n = blockIdx.y;
  int b0 = blockIdx.x * 128;
  int w = tid >> 6, lane = tid & 63, q = lane >> 4, rl = lane & 15;
  if (tid < HID) bc1f[tid] = ldin(bc1_g, n * HID + tid, bf);
  const u16* WT = Wc1t + (size_t)n * HID * 256;

  float4f acc[2][8] = {};
  for (int ph = 0; ph < 2; ph++) {
    const u32* su = (const u32*)(ph == 0 ? SEi : OT);
    for (int idx = tid; idx < 128 * 64; idx += 256) {
      int row = idx >> 6, c = idx & 63;
      ((u32*)&Xt[row * KP])[c] = su[((size_t)n * BATCH + b0 + row) * 64 + c];
    }
    __syncthreads();
    #pragma unroll
    for (int kc = 0; kc < 4; kc++) {
      int ko = ph * HID + kc * 32;
      short8 a0 = *(const short8*)&Xt[((2 * w) * 16 + rl) * KP + kc * 32 + q * 8];
      short8 a1 = *(const short8*)&Xt[((2 * w + 1) * 16 + rl) * KP + kc * 32 + q * 8];
      #pragma unroll
      for (int nt = 0; nt < 8; nt++) {
        short8 bb = *(const short8*)(WT + (size_t)(nt * 16 + rl) * 256 + ko + q * 8);
        acc[0][nt] = MFMA16(a0, bb, acc[0][nt]);
        acc[1][nt] = MFMA16(a1, bb, acc[1][nt]);
      }
    }
    __syncthreads();
  }
  u16* ht = Xt;
  #pragma unroll
  for (int mi = 0; mi < 2; mi++)
    #pragma unroll
    for (int nt = 0; nt < 8; nt++)
      #pragma unroll
      for (int r = 0; r < 4; r++) {
        int row = (2 * w + mi) * 16 + q * 4 + r, col = nt * 16 + rl;
        ht[row * KP + col] = f2bf(lrelu(acc[mi][nt][r] + bc1f[col]));
      }
  for (int idx = tid; idx < HID * AD; idx += 256)
    wc2h[idx] = ldbf(Wc2_g, (size_t)n * HID * AD + idx, bf);
  if (tid < 128) {
    size_t base = ((size_t)n * BATCH + b0 + tid) * AD;
    float best = ldin(a_g, base, bf); int bi = 0;
    for (int o = 1; o < AD; o++) {
      float v = ldin(a_g, base + o, bf);
      if (v > best) { best = v; bi = o; }   // strict > = first-max
    }
    amax[tid] = bi;
  }
  __syncthreads();
  {
    int b = tid >> 1, half = tid & 1;
    int col = amax[b];
    float acq = 0.f;
    const u16* hr = &ht[b * KP + half * 64];
    #pragma unroll
    for (int k = 0; k < 64; k++)
      acq = fmaf(bf2f(hr[k]), bf2f(wc2h[(half * 64 + k) * AD + col]), acq);
    acq += __shfl_xor(acq, 1);
    if (half == 0) {
      float v = acq + ldin(bc2_g, n * AD + col, bf);
      size_t oidx = (size_t)n * BATCH + b0 + b;
      if (bf) ((u16*)qo)[oidx] = f2bf(v);
      else    ((float*)qo)[oidx] = v;
    }
  }
}

extern "C" void kernel_launch(void* const* d_in, const int* in_sizes, int n_in,
                              void* d_out, int out_size, void* d_ws, size_t ws_size,
                              hipStream_t stream) {
  const void* s   = d_in[0];
  const void* a   = d_in[1];
  const void* Wsa = d_in[2];
  const void* bsa = d_in[3];
  const void* Wse = d_in[4];
  const void* bse = d_in[5];
  const void* Wk  = d_in[6];
  const void* Wsl = d_in[7];
  const void* Wv  = d_in[8];
  const void* bv  = d_in[9];
  const void* Wc1 = d_in[10];
  const void* bc1 = d_in[11];
  const void* Wc2 = d_in[12];
  const void* bc2 = d_in[13];

  char* ws = (char*)d_ws;
  int*   flag  = (int*)ws;
  float* part  = (float*)(ws + 256);
  u16*   Wsa_t = (u16*)(ws + 169216);
  u16*   Wse_t = (u16*)(ws + 382208);
  u16*   Wp_t  = (u16*)(ws + 529664);
  u16*   Wc1t  = (u16*)(ws + 634112);
  u16*   E     = (u16*)(ws + 1158400);
  u16*   SEb   = (u16*)(ws + 1158400 + 33554432ull);
  u16*   OT    = (u16*)(ws + 1158400 + 2ull * 33554432ull);

  k_stats<<<256, 256, 0, stream>>>(s, a, flag, part);
  k_wprep<<<60, 256, 0, stream>>>(Wsa, Wse, Wsl, Wk, Wv, Wc1, flag, Wsa_t, Wse_t, Wp_t, Wc1t);
  k_enc2<<<dim3(BATCH / 128, NA), 256, 0, stream>>>(s, a, Wsa_t, bsa, Wse_t, bse, part, flag, E, SEb);
  k_pattn5<<<BATCH / 8, 256, 0, stream>>>(E, SEb, Wp_t, bv, flag, OT);
  k_critic<<<dim3(BATCH / 128, NA), 256, 0, stream>>>(SEb, OT, a, Wc1t, bc1, Wc2, bc2, flag, d_out);
}

// Round 9
// 277.557 us; speedup vs baseline: 1.2109x; 1.1196x over previous
//
#include <hip/hip_runtime.h>

// Attention_Critic on MI355X — round 9: round-6 structure (best: 286us) +
//  - k_prep: stats and wprep merged into one launch (per-block dtype detect)
//  - k_pattn6: E-rows prefetched into registers at kernel start (cross-barrier
//    software pipeline; hides the E-restage global latency behind the sel phase)
// enc2/critic byte-identical to round 6. No shfl store packing (round-8 lesson).
//
// ws layout (bytes):
//   [0,256)        int flag (1 = bf16 inputs, 0 = f32)
//   [256,+163840)  stats partials f32 [8][32][80][2]
//   [169216,...)   Wsa_t bf16 [8][128 col][104 k]
//   [382208,...)   Wse_t bf16 [8][128 col][72 k]
//   [529664,...)   Wp_t  bf16 [4 p][3 mat][32 d][136 k]  (mat 0=sel,1=key,2=val)
//   [634112,...)   Wc1t  bf16 [8][128 col][256 k]
//   [1158400,+32M) E   bf16 [8][16384][128]
//   [+32M,+64M)    SE  bf16 [8][16384][128]
//   [+64M,+96M)    OT  bf16 [8][16384][128]

typedef unsigned short u16;
typedef unsigned int u32;

#define NA 8
#define BATCH 16384
#define SD 64
#define AD 16
#define IND 80
#define HID 128
#define HEADS 4
#define ATT 32
#define EPS 1e-5f
#define KP 136    // u16 stride, 128-k tiles
#define KP3 104   // u16 stride, 96-k tiles (Wsa_t)
#define KPS 72    // u16 stride, 64-k tiles (Wse_t)
#define SP 34     // u16 stride, 32-wide sel/key tiles
#define VTS 68    // u16 stride, valt [32 d][64 row']
#define WBS 24    // u16 stride, softmax weight tiles

using short8 = __attribute__((ext_vector_type(8))) short;
using float4f = __attribute__((ext_vector_type(4))) float;
#define MFMA16(a, b, c) __builtin_amdgcn_mfma_f32_16x16x32_bf16((a), (b), (c), 0, 0, 0)

__device__ __forceinline__ float bf2f(u16 u) { union { u32 i; float f; } v; v.i = ((u32)u) << 16; return v.f; }
__device__ __forceinline__ float lo2f(u32 w) { union { u32 i; float f; } v; v.i = w << 16; return v.f; }
__device__ __forceinline__ float hi2f(u32 w) { union { u32 i; float f; } v; v.i = w & 0xffff0000u; return v.f; }
__device__ __forceinline__ u16 f2bf(float f) {
  union { float f; u32 i; } v; v.f = f;
  u32 x = v.i;
  x += 0x7fffu + ((x >> 16) & 1u);   // RNE
  return (u16)(x >> 16);
}
__device__ __forceinline__ float lrelu(float x) { return x > 0.f ? x : 0.01f * x; }
__device__ __forceinline__ float ldin(const void* p, size_t i, bool bf) {
  return bf ? bf2f(((const u16*)p)[i]) : ((const float*)p)[i];
}
__device__ __forceinline__ u16 ldbf(const void* p, size_t i, bool bf) {
  return bf ? ((const u16*)p)[i] : f2bf(((const float*)p)[i]);
}
__device__ __forceinline__ short8 lds_s8(const u16* p) {   // 16B LDS load, 4B-aligned ok
  union { short8 v; u32 u[4]; } t;
  const u32* q = (const u32*)p;
  t.u[0] = q[0]; t.u[1] = q[1]; t.u[2] = q[2]; t.u[3] = q[3];
  return t.v;
}

// ---------------- K1: merged BN stats + weight prep (per-block dtype detect) ----------------
// blocks [0,256): stats; [256,288): Wc1; [288,296): Wsa; [296,304): Wse; [304,316): Wp.
__global__ __launch_bounds__(256) void k_prep(
    const void* __restrict__ s, const void* __restrict__ a,
    const void* __restrict__ Wsa, const void* __restrict__ Wse,
    const void* __restrict__ Wsl, const void* __restrict__ Wk, const void* __restrict__ Wv,
    const void* __restrict__ Wc1,
    int* __restrict__ flag, float* __restrict__ part,
    u16* __restrict__ Wsa_t, u16* __restrict__ Wse_t, u16* __restrict__ Wp_t, u16* __restrict__ Wc1t) {
  __shared__ u16 T[80 * 130];
  __shared__ float S0[256], Q0[256], S1[256], Q1[256];
  __shared__ int cnt[2];
  int tid = threadIdx.x;
  if (tid < 2) cnt[tid] = 0;
  __syncthreads();
  {   // local dtype detection (all blocks)
    u32 wv = ((const u32*)s)[tid];
    u32 lo = wv & 0xffffu, e = (lo >> 7) & 0xffu;
    if (lo == 0u || lo == 0x8000u) atomicAdd(&cnt[1], 1);
    else if (e < 0x70u || e > 0x8fu) atomicAdd(&cnt[0], 1);
  }
  __syncthreads();
  bool bf = !(cnt[0] >= 64 || cnt[1] >= 192);
  if (blockIdx.x == 0 && tid == 0) *flag = bf ? 1 : 0;
  int blkr = blockIdx.x;
  if (blkr < 256) {   // ---- stats ----
    int blk = blkr, n = blk >> 5, c = blk & 31, b0 = c << 9;
    {
      int f2 = tid & 31, rg = tid >> 5;
      float s0 = 0.f, s1 = 0.f, q0 = 0.f, q1 = 0.f;
      for (int i = 0; i < 64; i++) {
        int b = b0 + rg + 8 * i;
        float x0, x1;
        if (bf) { u32 wv = ((const u32*)s)[((size_t)n * BATCH + b) * 32 + f2]; x0 = lo2f(wv); x1 = hi2f(wv); }
        else { const float* sf = (const float*)s + ((size_t)n * BATCH + b) * 64 + 2 * f2; x0 = sf[0]; x1 = sf[1]; }
        s0 += x0; q0 += x0 * x0; s1 += x1; q1 += x1 * x1;
      }
      S0[tid] = s0; Q0[tid] = q0; S1[tid] = s1; Q1[tid] = q1;
    }
    __syncthreads();
    if (tid < 64) {
      int f2 = tid >> 1, odd = tid & 1;
      float S = 0.f, Q = 0.f;
      for (int rg = 0; rg < 8; rg++) {
        int ix = rg * 32 + f2;
        S += odd ? S1[ix] : S0[ix];
        Q += odd ? Q1[ix] : Q0[ix];
      }
      float* p = part + ((size_t)blk * IND + tid) * 2;
      p[0] = S; p[1] = Q;
    }
    __syncthreads();
    {
      int f2 = tid & 7, rg = tid >> 3;
      float s0 = 0.f, s1 = 0.f, q0 = 0.f, q1 = 0.f;
      for (int i = 0; i < 16; i++) {
        int b = b0 + rg + 32 * i;
        float x0, x1;
        if (bf) { u32 wv = ((const u32*)a)[((size_t)n * BATCH + b) * 8 + f2]; x0 = lo2f(wv); x1 = hi2f(wv); }
        else { const float* af = (const float*)a + ((size_t)n * BATCH + b) * 16 + 2 * f2; x0 = af[0]; x1 = af[1]; }
        s0 += x0; q0 += x0 * x0; s1 += x1; q1 += x1 * x1;
      }
      S0[tid] = s0; Q0[tid] = q0; S1[tid] = s1; Q1[tid] = q1;
    }
    __syncthreads();
    if (tid < 16) {
      int f2 = tid >> 1, odd = tid & 1;
      float S = 0.f, Q = 0.f;
      for (int rg = 0; rg < 32; rg++) {
        int ix = rg * 8 + f2;
        S += odd ? S1[ix] : S0[ix];
        Q += odd ? Q1[ix] : Q0[ix];
      }
      float* p = part + ((size_t)blk * IND + SD + tid) * 2;
      p[0] = S; p[1] = Q;
    }
    return;
  }
  int blk = blkr - 256;   // ---- weight prep ----
  if (blk < 32) {                       // Wc1 [n][256][128] -> Wc1t [n][128][256]
    int n = blk >> 2, k0 = (blk & 3) * 64;
    for (int i = tid; i < 64 * 128; i += 256) {
      int kr = i >> 7, cc = i & 127;
      T[kr * 130 + cc] = ldbf(Wc1, ((size_t)n * 256 + k0 + kr) * 128 + cc, bf);
    }
    __syncthreads();
    for (int i = tid; i < 128 * 64; i += 256) {
      int col = i >> 6, kk = i & 63;
      Wc1t[((size_t)n * 128 + col) * 256 + k0 + kk] = T[kk * 130 + col];
    }
  } else if (blk < 40) {                // Wsa -> Wsa_t
    int n = blk - 32;
    for (int i = tid; i < 80 * 128; i += 256) {
      int kr = i >> 7, cc = i & 127;
      T[kr * 130 + cc] = ldbf(Wsa, ((size_t)n * IND + kr) * 128 + cc, bf);
    }
    __syncthreads();
    for (int i = tid; i < 128 * KP3; i += 256) {
      int col = i / KP3, k = i - col * KP3;
      Wsa_t[((size_t)n * 128 + col) * KP3 + k] = (k < IND) ? T[k * 130 + col] : (u16)0;
    }
  } else if (blk < 48) {                // Wse -> Wse_t
    int n = blk - 40;
    for (int i = tid; i < 64 * 128; i += 256) {
      int kr = i >> 7, cc = i & 127;
      T[kr * 130 + cc] = ldbf(Wse, ((size_t)n * SD + kr) * 128 + cc, bf);
    }
    __syncthreads();
    for (int i = tid; i < 128 * KPS; i += 256) {
      int col = i / KPS, k = i - col * KPS;
      Wse_t[((size_t)n * 128 + col) * KPS + k] = (k < SD) ? T[k * 130 + col] : (u16)0;
    }
  } else {                              // Wp -> Wp_t
    int pm = blk - 48, p = pm / 3, mat = pm - 3 * p;
    const void* W = (mat == 0) ? Wsl : (mat == 1) ? Wk : Wv;
    for (int i = tid; i < 128 * 32; i += 256) {
      int kr = i >> 5, d = i & 31;
      T[kr * 34 + d] = ldbf(W, ((size_t)p * HID + kr) * ATT + d, bf);
    }
    __syncthreads();
    for (int i = tid; i < 32 * KP; i += 256) {
      int d = i / KP, k = i - d * KP;
      Wp_t[(((size_t)p * 3 + mat) * ATT + d) * KP + k] = (k < HID) ? T[k * 34 + d] : (u16)0;
    }
  }
}

// ---------------- K2: MFMA encoders (byte-identical to round 6) ----------------
// LDS: sanb 26624 + mst 640 + biases 1024 = 28288 B (5 blocks/CU)
__global__ __launch_bounds__(256) void k_enc2(const void* __restrict__ s, const void* __restrict__ a,
    const u16* __restrict__ Wsa_t, const void* __restrict__ bsa,
    const u16* __restrict__ Wse_t, const void* __restrict__ bse,
    const float* __restrict__ part, const int* __restrict__ flag,
    u16* __restrict__ E, u16* __restrict__ SEo) {
  __shared__ __align__(16) u16 sanb[128 * KP3];
  __shared__ float mst[IND * 2];
  __shared__ float bsaf[HID], bsef[HID];
  bool bf = (*flag != 0);
  int tid = threadIdx.x;
  int n = blockIdx.y;
  int b0 = blockIdx.x * 128;
  int w = tid >> 6, lane = tid & 63, q = lane >> 4, rl = lane & 15;
  if (tid < HID) { bsaf[tid] = ldin(bsa, n * HID + tid, bf); bsef[tid] = ldin(bse, n * HID + tid, bf); }
  if (tid < IND) {   // folded stats finalize
    float S = 0.f, Q = 0.f;
    for (int c = 0; c < 32; c++) {
      const float* pp = part + ((size_t)(n * 32 + c) * IND + tid) * 2;
      S += pp[0]; Q += pp[1];
    }
    float mean = S * (1.f / BATCH);
    float var = Q * (1.f / BATCH) - mean * mean;
    mst[tid * 2] = mean;
    mst[tid * 2 + 1] = rsqrtf(var + EPS);
  }
  __syncthreads();
  for (int i = tid; i < 128 * 32; i += 256) {          // s-part k 0..63
    int row = i >> 5, kp = i & 31;
    float x0, x1;
    if (bf) { u32 wv = ((const u32*)s)[((size_t)n * BATCH + b0 + row) * 32 + kp]; x0 = lo2f(wv); x1 = hi2f(wv); }
    else { const float* sf = (const float*)s + ((size_t)n * BATCH + b0 + row) * 64 + 2 * kp; x0 = sf[0]; x1 = sf[1]; }
    int k = 2 * kp;
    u32 o = (u32)f2bf((x0 - mst[k * 2]) * mst[k * 2 + 1]) |
            ((u32)f2bf((x1 - mst[k * 2 + 2]) * mst[k * 2 + 3]) << 16);
    *(u32*)&sanb[row * KP3 + k] = o;
  }
  for (int i = tid; i < 128 * 8; i += 256) {           // a-part k 64..79
    int row = i >> 3, kp = i & 7;
    float x0, x1;
    if (bf) { u32 wv = ((const u32*)a)[((size_t)n * BATCH + b0 + row) * 8 + kp]; x0 = lo2f(wv); x1 = hi2f(wv); }
    else { const float* af = (const float*)a + ((size_t)n * BATCH + b0 + row) * 16 + 2 * kp; x0 = af[0]; x1 = af[1]; }
    int k = SD + 2 * kp;
    u32 o = (u32)f2bf((x0 - mst[k * 2]) * mst[k * 2 + 1]) |
            ((u32)f2bf((x1 - mst[k * 2 + 2]) * mst[k * 2 + 3]) << 16);
    *(u32*)&sanb[row * KP3 + k] = o;
  }
  for (int i = tid; i < 128 * 12; i += 256) {          // zero pad k 80..103
    int row = i / 12, c2 = i - row * 12;
    *(u32*)&sanb[row * KP3 + IND + 2 * c2] = 0u;
  }
  __syncthreads();
  const u16* WA = Wsa_t + (size_t)n * HID * KP3;
  const u16* WS = Wse_t + (size_t)n * HID * KPS;
  {  // E = lrelu(bn(sa) @ Wsa + bsa), K=96
    float4f acc[2][8] = {};
    #pragma unroll
    for (int kc = 0; kc < 3; kc++) {
      short8 a0 = *(const short8*)&sanb[((2 * w) * 16 + rl) * KP3 + kc * 32 + q * 8];
      short8 a1 = *(const short8*)&sanb[((2 * w + 1) * 16 + rl) * KP3 + kc * 32 + q * 8];
      #pragma unroll
      for (int nt = 0; nt < 8; nt++) {
        short8 bb = *(const short8*)(WA + (size_t)(nt * 16 + rl) * KP3 + kc * 32 + q * 8);
        acc[0][nt] = MFMA16(a0, bb, acc[0][nt]);
        acc[1][nt] = MFMA16(a1, bb, acc[1][nt]);
      }
    }
    #pragma unroll
    for (int mi = 0; mi < 2; mi++)
      #pragma unroll
      for (int nt = 0; nt < 8; nt++)
        #pragma unroll
        for (int r = 0; r < 4; r++) {
          int row = (2 * w + mi) * 16 + q * 4 + r, col = nt * 16 + rl;
          E[((size_t)n * BATCH + b0 + row) * HID + col] = f2bf(lrelu(acc[mi][nt][r] + bsaf[col]));
        }
  }
  {  // SE = lrelu(bn(s) @ Wse + bse), K=64
    float4f acc[2][8] = {};
    #pragma unroll
    for (int kc = 0; kc < 2; kc++) {
      short8 a0 = *(const short8*)&sanb[((2 * w) * 16 + rl) * KP3 + kc * 32 + q * 8];
      short8 a1 = *(const short8*)&sanb[((2 * w + 1) * 16 + rl) * KP3 + kc * 32 + q * 8];
      #pragma unroll
      for (int nt = 0; nt < 8; nt++) {
        short8 bb = *(const short8*)(WS + (size_t)(nt * 16 + rl) * KPS + kc * 32 + q * 8);
        acc[0][nt] = MFMA16(a0, bb, acc[0][nt]);
        acc[1][nt] = MFMA16(a1, bb, acc[1][nt]);
      }
    }
    #pragma unroll
    for (int mi = 0; mi < 2; mi++)
      #pragma unroll
      for (int nt = 0; nt < 8; nt++)
        #pragma unroll
        for (int r = 0; r < 4; r++) {
          int row = (2 * w + mi) * 16 + q * 4 + r, col = nt * 16 + rl;
          SEo[((size_t)n * BATCH + b0 + row) * HID + col] = f2bf(lrelu(acc[mi][nt][r] + bsef[col]));
        }
  }
}

// ---------------- K3: projections + full-MFMA attention, E prefetched in regs ----------------
// LDS: X 17408 + selb 17408 + keyb 4352 + valt 4352 + wb 3072 + bvf 512 = 47104 B
__global__ __launch_bounds__(256) void k_pattn6(
    const u16* __restrict__ E, const u16* __restrict__ SEi,
    const u16* __restrict__ Wp_t, const void* __restrict__ bv_g,
    const int* __restrict__ flag, u16* __restrict__ OT) {
  __shared__ __align__(16) u16 X[64 * KP];
  __shared__ __align__(16) u16 selb[HEADS * 64 * SP];   // [p][row'=b*8+agent][d]
  __shared__ __align__(16) u16 keyb[64 * SP];
  __shared__ __align__(16) u16 valt[ATT * VTS];         // [d][row']
  __shared__ __align__(16) u16 wb[64 * WBS];            // softmax weights
  __shared__ float bvf[HID];
  bool bf = (*flag != 0);
  int tid = threadIdx.x;
  int b0 = blockIdx.x * 8;
  int w = tid >> 6, lane = tid & 63, q = lane >> 4, rl = lane & 15;
  if (tid < HID) bvf[tid] = ldin(bv_g, tid, bf);
  // ---- prefetch E rows into registers (independent loads, issued first) ----
  u32 pre[16];
  {
    const u32* su = (const u32*)E;
    #pragma unroll
    for (int t = 0; t < 16; t++) {
      int idx = tid + t * 256;
      int row = idx >> 6, c = idx & 63;
      pre[t] = su[(((size_t)(row >> 3)) * BATCH + b0 + (row & 7)) * 64 + c];
    }
  }
  // stage X <- SE
  {
    const u32* su = (const u32*)SEi;
    for (int idx = tid; idx < 64 * 64; idx += 256) {
      int row = idx >> 6, c = idx & 63;
      ((u32*)&X[row * KP])[c] = su[(((size_t)(row >> 3)) * BATCH + b0 + (row & 7)) * 64 + c];
    }
  }
  __syncthreads();   // A
  // phase 1: sel for all heads, B-frags straight from global
  #pragma unroll
  for (int p = 0; p < HEADS; p++) {
    const u16* WB = Wp_t + (size_t)(p * 3) * ATT * KP;
    float4f acs[2] = {};
    #pragma unroll
    for (int kc = 0; kc < 4; kc++) {
      short8 af = *(const short8*)&X[(w * 16 + rl) * KP + kc * 32 + q * 8];
      #pragma unroll
      for (int nt = 0; nt < 2; nt++) {
        short8 bb = *(const short8*)(WB + (size_t)(nt * 16 + rl) * KP + kc * 32 + q * 8);
        acs[nt] = MFMA16(af, bb, acs[nt]);
      }
    }
    #pragma unroll
    for (int nt = 0; nt < 2; nt++)
      #pragma unroll
      for (int r = 0; r < 4; r++) {
        int m = w * 16 + q * 4 + r;
        int rowp = ((m & 7) << 3) | (m >> 3);
        selb[(p * 64 + rowp) * SP + nt * 16 + rl] = f2bf(acs[nt][r]);
      }
  }
  __syncthreads();   // B: SE reads done
  // write prefetched E rows into X (no global latency here)
  {
    #pragma unroll
    for (int t = 0; t < 16; t++) {
      int idx = tid + t * 256;
      int row = idx >> 6, c = idx & 63;
      ((u32*)&X[row * KP])[c] = pre[t];
    }
  }
  __syncthreads();   // C
  // phase 2: per head: key/val -> MFMA logits -> shfl softmax -> MFMA weighted sum
  const float scale = 0.17677669529663687f;
  for (int p = 0; p < HEADS; p++) {
    const u16* WK = Wp_t + (size_t)(p * 3 + 1) * ATT * KP;
    const u16* WV = Wp_t + (size_t)(p * 3 + 2) * ATT * KP;
    {
      float4f ak[2] = {}, av[2] = {};
      #pragma unroll
      for (int kc = 0; kc < 4; kc++) {
        short8 af = *(const short8*)&X[(w * 16 + rl) * KP + kc * 32 + q * 8];
        #pragma unroll
        for (int nt = 0; nt < 2; nt++) {
          short8 bk = *(const short8*)(WK + (size_t)(nt * 16 + rl) * KP + kc * 32 + q * 8);
          ak[nt] = MFMA16(af, bk, ak[nt]);
          short8 bv8 = *(const short8*)(WV + (size_t)(nt * 16 + rl) * KP + kc * 32 + q * 8);
          av[nt] = MFMA16(af, bv8, av[nt]);
        }
      }
      #pragma unroll
      for (int nt = 0; nt < 2; nt++)
        #pragma unroll
        for (int r = 0; r < 4; r++) {
          int m = w * 16 + q * 4 + r;
          int rowp = ((m & 7) << 3) | (m >> 3);
          int d = nt * 16 + rl;
          keyb[rowp * SP + d] = f2bf(ak[nt][r]);
          valt[d * VTS + rowp] = f2bf(lrelu(av[nt][r] + bvf[p * ATT + d]));
        }
    }
    __syncthreads();   // D: selb/keyb/valt visible
    {
      short8 sa = lds_s8(&selb[(p * 64 + w * 16 + rl) * SP + q * 8]);
      short8 kb = lds_s8(&keyb[(w * 16 + rl) * SP + q * 8]);
      float4f zc = {};
      float4f c = MFMA16(sa, kb, zc);
      int nn = rl;
      #pragma unroll
      for (int r = 0; r < 4; r++) {
        int row = q * 4 + r;
        float x = c[r] * scale;
        if (row == nn) x = -1e9f;                    // self-mask (same b, i==j)
        float mx = x;
        mx = fmaxf(mx, __shfl_xor(mx, 1));
        mx = fmaxf(mx, __shfl_xor(mx, 2));
        mx = fmaxf(mx, __shfl_xor(mx, 4));
        float e = __expf(x - mx);
        float ssum = e;
        ssum += __shfl_xor(ssum, 1);
        ssum += __shfl_xor(ssum, 2);
        ssum += __shfl_xor(ssum, 4);
        float wv = e / ssum;
        if ((row >> 3) != (nn >> 3)) wv = 0.f;       // zero cross-b junk
        wb[(w * 16 + row) * WBS + nn] = f2bf(wv);    // wave-private rows
      }
      short8 aw;
      if (q < 2) aw = *(const short8*)&wb[(w * 16 + rl) * WBS + q * 8];
      else { short8 z = {}; aw = z; }
      float4f o[2] = {};
      #pragma unroll
      for (int nt = 0; nt < 2; nt++) {
        short8 bv8 = lds_s8(&valt[(nt * 16 + rl) * VTS + w * 16 + (q & 1) * 8]);
        o[nt] = MFMA16(aw, bv8, o[nt]);
      }
      #pragma unroll
      for (int nt = 0; nt < 2; nt++)
        #pragma unroll
        for (int r = 0; r < 4; r++) {
          int row = q * 4 + r;
          int b = 2 * w + (row >> 3), i = row & 7;
          OT[((size_t)i * BATCH + b0 + b) * HID + p * ATT + nt * 16 + rl] = f2bf(o[nt][r]);
        }
    }
    __syncthreads();   // E_p: scratch reads done before next head's writes
  }
}

// ---------------- K4: critic MFMA GEMM + argmax gather (byte-identical to round 6) ----------------
// LDS: Xt 34816 + wc2f 8192 + bc1f 512 + amax 512 = 44032 B
__global__ __launch_bounds__(256) void k_critic(
    const u16* __restrict__ SEi, const u16* __restrict__ OT, const void* __restrict__ a_g,
    const u16* __restrict__ Wc1t, const void* __restrict__ bc1_g,
    const void* __restrict__ Wc2_g, const void* __restrict__ bc2_g,
    const int* __restrict__ flag, void* __restrict__ qo) {
  __shared__ __align__(16) u16 Xt[128 * KP];   // input rows; reused as ht
  __shared__ float wc2f[HID * AD];
  __shared__ float bc1f[HID];
  __shared__ int amax[128];
  bool bf = (*flag != 0);
  int tid = threadIdx.x;
  int n = blockIdx.y;
  int b0 = blockIdx.x * 128;
  int w = tid >> 6, lane = tid & 63, q = lane >> 4, rl = lane & 15;
  if (tid < HID) bc1f[tid] = ldin(bc1_g, n * HID + tid, bf);
  const u16* WT = Wc1t + (size_t)n * HID * 256;

  float4f acc[2][8] = {};
  for (int ph = 0; ph < 2; ph++) {
    const u32* su = (const u32*)(ph == 0 ? SEi : OT);
    for (int idx = tid; idx < 128 * 64; idx += 256) {
      int row = idx >> 6, c = idx & 63;
      ((u32*)&Xt[row * KP])[c] = su[((size_t)n * BATCH + b0 + row) * 64 + c];
    }
    __syncthreads();
    #pragma unroll
    for (int kc = 0; kc < 4; kc++) {
      int ko = ph * HID + kc * 32;
      short8 a0 = *(const short8*)&Xt[((2 * w) * 16 + rl) * KP + kc * 32 + q * 8];
      short8 a1 = *(const short8*)&Xt[((2 * w + 1) * 16 + rl) * KP + kc * 32 + q * 8];
      #pragma unroll
      for (int nt = 0; nt < 8; nt++) {
        short8 bb = *(const short8*)(WT + (size_t)(nt * 16 + rl) * 256 + ko + q * 8);
        acc[0][nt] = MFMA16(a0, bb, acc[0][nt]);
        acc[1][nt] = MFMA16(a1, bb, acc[1][nt]);
      }
    }
    __syncthreads();
  }
  u16* ht = Xt;
  #pragma unroll
  for (int mi = 0; mi < 2; mi++)
    #pragma unroll
    for (int nt = 0; nt < 8; nt++)
      #pragma unroll
      for (int r = 0; r < 4; r++) {
        int row = (2 * w + mi) * 16 + q * 4 + r, col = nt * 16 + rl;
        ht[row * KP + col] = f2bf(lrelu(acc[mi][nt][r] + bc1f[col]));
      }
  for (int idx = tid; idx < HID * AD; idx += 256)
    wc2f[idx] = ldin(Wc2_g, (size_t)n * HID * AD + idx, bf);
  if (tid < 128) {
    size_t base = ((size_t)n * BATCH + b0 + tid) * AD;
    float best = ldin(a_g, base, bf); int bi = 0;
    for (int o = 1; o < AD; o++) {
      float v = ldin(a_g, base + o, bf);
      if (v > best) { best = v; bi = o; }   // strict > = first-max
    }
    amax[tid] = bi;
  }
  __syncthreads();
  {
    int b = tid >> 1, half = tid & 1;
    int col = amax[b];
    float acq = 0.f;
    const u16* hr = &ht[b * KP + half * 64];
    #pragma unroll
    for (int k = 0; k < 64; k++)
      acq = fmaf(bf2f(hr[k]), wc2f[(half * 64 + k) * AD + col], acq);
    acq += __shfl_xor(acq, 1);
    if (half == 0) {
      float v = acq + ldin(bc2_g, n * AD + col, bf);
      size_t oidx = (size_t)n * BATCH + b0 + b;
      if (bf) ((u16*)qo)[oidx] = f2bf(v);
      else    ((float*)qo)[oidx] = v;
    }
  }
}

extern "C" void kernel_launch(void* const* d_in, const int* in_sizes, int n_in,
                              void* d_out, int out_size, void* d_ws, size_t ws_size,
                              hipStream_t stream) {
  const void* s   = d_in[0];
  const void* a   = d_in[1];
  const void* Wsa = d_in[2];
  const void* bsa = d_in[3];
  const void* Wse = d_in[4];
  const void* bse = d_in[5];
  const void* Wk  = d_in[6];
  const void* Wsl = d_in[7];
  const void* Wv  = d_in[8];
  const void* bv  = d_in[9];
  const void* Wc1 = d_in[10];
  const void* bc1 = d_in[11];
  const void* Wc2 = d_in[12];
  const void* bc2 = d_in[13];

  char* ws = (char*)d_ws;
  int*   flag  = (int*)ws;
  float* part  = (float*)(ws + 256);
  u16*   Wsa_t = (u16*)(ws + 169216);
  u16*   Wse_t = (u16*)(ws + 382208);
  u16*   Wp_t  = (u16*)(ws + 529664);
  u16*   Wc1t  = (u16*)(ws + 634112);
  u16*   E     = (u16*)(ws + 1158400);
  u16*   SEb   = (u16*)(ws + 1158400 + 33554432ull);
  u16*   OT    = (u16*)(ws + 1158400 + 2ull * 33554432ull);

  k_prep<<<316, 256, 0, stream>>>(s, a, Wsa, Wse, Wsl, Wk, Wv, Wc1,
                                  flag, part, Wsa_t, Wse_t, Wp_t, Wc1t);
  k_enc2<<<dim3(BATCH / 128, NA), 256, 0, stream>>>(s, a, Wsa_t, bsa, Wse_t, bse, part, flag, E, SEb);
  k_pattn6<<<BATCH / 8, 256, 0, stream>>>(E, SEb, Wp_t, bv, flag, OT);
  k_critic<<<dim3(BATCH / 128, NA), 256, 0, stream>>>(SEb, OT, a, Wc1t, bc1, Wc2, bc2, flag, d_out);
}